// Round 2
// baseline (637.072 us; speedup 1.0000x reference)
//
#include <hip/hip_runtime.h>

// Conv4d via implicit GEMM on MFMA (bf16 in, fp32 accum).
// x (2,16,20^4) f32, w (16,32,3^4) f32 -> out (2,32,18^4) f32
//
// Decomposition: out[oc][pos] = sum over 81 taps of W_tap[32 oc][16 ic] * X[16 ic][32 pos]
//   -> one v_mfma_f32_32x32x16_bf16 per (tap, 32-pos tile).  K = 16 = IC exactly.
//
// Pre-pass 1: x  -> x_t  bf16 NHWC  [n][i'][j'][k][l][ic]   (10.24 MB in d_ws)
// Pre-pass 2: w  -> w_t  bf16       [tap][oc][ic]           (82.9 KB in d_ws)
// Conv: block=(i,j,n), 256 thr / 4 waves; per (a,b) of 9: stage contiguous
//   12.8KB slab to LDS (double-buffered, reg-staged prefetch), A-frags from
//   global w_t (L2-resident), inner 9 (c,d) taps x 3 pos-tiles/wave: 1
//   ds_read_b128 + 1 MFMA each.

typedef unsigned short ushort_t;
typedef __attribute__((ext_vector_type(8)))  __bf16 bf16x8;
typedef __attribute__((ext_vector_type(16))) float  f32x16;
typedef __attribute__((ext_vector_type(4)))  unsigned int uint4v;

__device__ __forceinline__ ushort_t f2bf(float f) {
    union { float f; unsigned int u; } v; v.f = f;
    unsigned int r = v.u + 0x7FFFu + ((v.u >> 16) & 1u);   // RNE
    return (ushort_t)(r >> 16);
}

// ---------- pre-pass: x (NCHW f32) -> x_t (NHWC bf16) ----------
// x strides (f32 elems): n 2560000, ic 160000, i 8000, j 400, (k,l)=p 1
// x_t strides (bf16 elems): n 2560000, i 128000, j 6400, p*16 + ic
__global__ __launch_bounds__(256) void xpose_x(const float* __restrict__ x,
                                               ushort_t* __restrict__ xt) {
    __shared__ ushort_t lt[6400];
    const int j = blockIdx.x, i = blockIdx.y, n = blockIdx.z;
    const int t = threadIdx.x;
    const float* xb = x + (size_t)n * 2560000 + (size_t)i * 8000 + (size_t)j * 400;
    #pragma unroll
    for (int ic = 0; ic < 16; ++ic) {
        const float* xr = xb + (size_t)ic * 160000;
        for (int s = t; s < 400; s += 256)
            lt[s * 16 + ic] = f2bf(xr[s]);
    }
    __syncthreads();
    uint4v* dst = (uint4v*)(xt + (size_t)n * 2560000 + (size_t)i * 128000 + (size_t)j * 6400);
    const uint4v* srcl = (const uint4v*)lt;
    for (int s = t; s < 800; s += 256) dst[s] = srcl[s];
}

// ---------- pre-pass: w (ic,oc,tap f32) -> w_t (tap,oc,ic bf16) ----------
__global__ __launch_bounds__(256) void xpose_w(const float* __restrict__ w,
                                               ushort_t* __restrict__ wt) {
    int s = blockIdx.x * 256 + threadIdx.x;
    if (s < 41472) {
        int ic = s / 2592, rem = s % 2592;
        int oc = rem / 81, tap = rem % 81;
        wt[tap * 512 + oc * 16 + ic] = f2bf(w[s]);
    }
}

// ---------- main conv ----------
__global__ __launch_bounds__(256, 3) void conv4d_mfma(
    const ushort_t* __restrict__ xt, const ushort_t* __restrict__ wt,
    float* __restrict__ out)
{
    __shared__ ushort_t lx[2][6400];   // double-buffered (k',l',ic) slab, 12.8KB each

    const int i = blockIdx.x, j = blockIdx.y, n = blockIdx.z;
    const int t = threadIdx.x;
    const int lane = t & 63, wv = t >> 6;
    const int col = lane & 31, ic8 = lane >> 5;

    // per-tile precompute (pos -> slab offset / out offset), invariant over taps
    int soff[3]; int pcs[3]; bool val[3];
    const int tbase = wv * 3;
    #pragma unroll
    for (int m = 0; m < 3; ++m) {
        int pos = (tbase + m) * 32 + col;
        val[m] = (pos < 324);
        int pc = val[m] ? pos : 323;
        int k_ = pc / 18, l_ = pc % 18;
        soff[m] = (k_ * 20 + l_) * 32 + ic8 * 16;  // BYTES into slab
        pcs[m] = pc;
    }
    const int ntile = (tbase < 9) ? 3 : 2;  // tiles 0..10 cover 324 pos; wave3 has 2

    f32x16 acc[3];
    #pragma unroll
    for (int m = 0; m < 3; ++m)
        #pragma unroll
        for (int r = 0; r < 16; ++r) acc[m][r] = 0.0f;

    const ushort_t* xbase = xt + (size_t)n * 2560000;

    // reg-staged prefetch of the 12.8KB slab: 800 16B chunks / 256 threads
    uint4v stg[4];
    {
        const uint4v* s4 = (const uint4v*)(xbase + (size_t)(i + 0) * 128000 + (size_t)(j + 0) * 6400);
        stg[0] = s4[t]; stg[1] = s4[t + 256]; stg[2] = s4[t + 512];
        if (t < 32) stg[3] = s4[t + 768];
    }
    {
        uint4v* d4 = (uint4v*)lx[0];
        d4[t] = stg[0]; d4[t + 256] = stg[1]; d4[t + 512] = stg[2];
        if (t < 32) d4[t + 768] = stg[3];
    }

    int cur = 0;
    for (int ab = 0; ab < 9; ++ab) {
        __syncthreads();   // slab[cur] visible; everyone done with slab[cur^1]

        // issue next slab's global loads early (hide HBM under compute)
        if (ab < 8) {
            int a = (ab + 1) / 3, b = (ab + 1) % 3;
            const uint4v* s4 = (const uint4v*)(xbase + (size_t)(i + a) * 128000 + (size_t)(j + b) * 6400);
            stg[0] = s4[t]; stg[1] = s4[t + 256]; stg[2] = s4[t + 512];
            if (t < 32) stg[3] = s4[t + 768];
        }

        // A fragments for this (a,b): 9 taps, straight from global (L2-resident)
        bf16x8 af[9];
        const ushort_t* wtb = wt + (ab * 9) * 512 + col * 16 + ic8 * 8;
        #pragma unroll
        for (int cd = 0; cd < 9; ++cd)
            af[cd] = *(const bf16x8*)(wtb + cd * 512);

        const char* lbase = (const char*)lx[cur];
        #pragma unroll
        for (int cd = 0; cd < 9; ++cd) {
            const int toff = ((cd / 3) * 20 + (cd % 3)) * 32;   // tap (c,d) byte shift
            for (int m = 0; m < ntile; ++m) {
                bf16x8 bv = *(const bf16x8*)(lbase + (soff[m] + toff));
                acc[m] = __builtin_amdgcn_mfma_f32_32x32x16_bf16(af[cd], bv, acc[m], 0, 0, 0);
            }
        }

        if (ab < 8) {
            uint4v* d4 = (uint4v*)lx[cur ^ 1];
            d4[t] = stg[0]; d4[t + 256] = stg[1]; d4[t + 512] = stg[2];
            if (t < 32) d4[t + 768] = stg[3];
            cur ^= 1;
        }
    }

    // epilogue: D layout col=lane&31, row=(r&3)+8*(r>>2)+4*(lane>>5)
    float* outn = out + (size_t)n * 32 * 104976 + (size_t)i * 5832 + (size_t)j * 324;
    #pragma unroll
    for (int m = 0; m < 3; ++m) {
        if (m >= ntile || !val[m]) continue;
        float* ob = outn + pcs[m];
        #pragma unroll
        for (int r = 0; r < 16; ++r) {
            int oc = (r & 3) + 8 * (r >> 2) + 4 * ic8;
            ob[(size_t)oc * 104976] = acc[m][r];
        }
    }
}

// ---------- fallback (fp32 direct, from round 1) if ws too small ----------
#define BLK 448
#define ACTIVE 432
__global__ __launch_bounds__(BLK) void conv4d_fp32(
    const float* __restrict__ x, const float* __restrict__ w,
    float* __restrict__ out)
{
    __shared__ float lds_x[3600];
    __shared__ float lds_w[81 * 33];
    const int i = blockIdx.x, j = blockIdx.y, n = blockIdx.z;
    const int t = threadIdx.x;
    const bool active = (t < ACTIVE);
    const int tt = active ? t : 0;
    const int ocb = tt / 54;
    const int kl = tt % 54;
    const int k = kl / 3;
    const int l0 = (kl % 3) * 6;
    const int oc0 = ocb * 4;
    float acc[4][6];
    #pragma unroll
    for (int u = 0; u < 4; ++u)
        #pragma unroll
        for (int q = 0; q < 6; ++q) acc[u][q] = 0.0f;
    const float* xn = x + (size_t)n * 2560000;
    for (int ic = 0; ic < 16; ++ic) {
        __syncthreads();
        const float* xb = xn + ic * 160000 + i * 8000 + j * 400;
        for (int s = t; s < 900; s += BLK) {
            const int ab = s / 100, rem = s % 100;
            const float4 v = *(const float4*)(xb + (ab / 3) * 8000 + (ab % 3) * 400 + rem * 4);
            *(float4*)(&lds_x[ab * 400 + rem * 4]) = v;
        }
        const float* wb = w + ic * 2592;
        for (int s = t; s < 2592; s += BLK)
            lds_w[(s % 81) * 33 + (s / 81)] = wb[s];
        __syncthreads();
        #pragma unroll
        for (int ab = 0; ab < 9; ++ab) {
            const float* xab = lds_x + ab * 400 + k * 20 + l0;
            #pragma unroll
            for (int c = 0; c < 3; ++c) {
                const float* xr = xab + c * 20;
                float xv[8];
                #pragma unroll
                for (int q = 0; q < 8; ++q) xv[q] = xr[q];
                const float* wr0 = lds_w + (ab * 3 + c) * 3 * 33 + oc0;
                #pragma unroll
                for (int d = 0; d < 3; ++d) {
                    const float* wr = wr0 + d * 33;
                    const float w0 = wr[0], w1 = wr[1], w2 = wr[2], w3 = wr[3];
                    #pragma unroll
                    for (int q = 0; q < 6; ++q) {
                        const float xx = xv[q + d];
                        acc[0][q] = fmaf(xx, w0, acc[0][q]);
                        acc[1][q] = fmaf(xx, w1, acc[1][q]);
                        acc[2][q] = fmaf(xx, w2, acc[2][q]);
                        acc[3][q] = fmaf(xx, w3, acc[3][q]);
                    }
                }
            }
        }
    }
    if (active) {
        float* ob = out + (size_t)(n * 32 + oc0) * 104976 + i * 5832 + j * 324 + k * 18 + l0;
        #pragma unroll
        for (int u = 0; u < 4; ++u)
            #pragma unroll
            for (int q = 0; q < 6; ++q) ob[u * 104976 + q] = acc[u][q];
    }
}

extern "C" void kernel_launch(void* const* d_in, const int* in_sizes, int n_in,
                              void* d_out, int out_size, void* d_ws, size_t ws_size,
                              hipStream_t stream) {
    const float* x = (const float*)d_in[0];
    const float* w = (const float*)d_in[1];
    float* out = (float*)d_out;

    const size_t XT_BYTES = 2u * 20u * 20u * 20u * 20u * 16u * 2u;  // 10,240,000
    const size_t WT_BYTES = 81u * 32u * 16u * 2u;                   // 82,944

    if (ws_size < XT_BYTES + WT_BYTES) {
        dim3 grid(18, 18, 2);
        conv4d_fp32<<<grid, BLK, 0, stream>>>(x, w, out);
        return;
    }

    ushort_t* xt = (ushort_t*)d_ws;
    ushort_t* wt = (ushort_t*)((char*)d_ws + XT_BYTES);

    xpose_w<<<dim3(162), 256, 0, stream>>>(w, wt);
    xpose_x<<<dim3(20, 20, 2), 256, 0, stream>>>(x, xt);
    conv4d_mfma<<<dim3(18, 18, 2), 256, 0, stream>>>(xt, wt, out);
}

// Round 3
// 59.036 us; speedup vs baseline: 10.7912x; 10.7912x over previous
//
#include <hip/hip_runtime.h>

// Conv4d via implicit GEMM on MFMA (bf16 in, fp32 accum).
// x (2,16,20^4) f32, w (16,32,3^4) f32 -> out (2,32,18^4) f32
//
// out[oc][pos] = sum over 81 taps of W_tap[32 oc][16 ic] * X_tap[16 ic][32 pos]
//   -> one v_mfma_f32_32x32x16_bf16 per (tap, 32-pos tile).  K = 16 = IC.
//
// R3 fix vs R2: the inner pos-tile loop had a RUNTIME trip count (ntile), so
// acc[m] was runtime-indexed -> compiler put accumulators in SCRATCH
// (VGPR_Count=44, WRITE_SIZE=1.07GB, 637us). Now fully unrolled m=0..2;
// wave3's dead 12th tile computes into a clamped LDS address and is dropped
// at the epilogue. All accumulator state register-resident.

typedef unsigned short ushort_t;
typedef __attribute__((ext_vector_type(8)))  __bf16 bf16x8;
typedef __attribute__((ext_vector_type(16))) float  f32x16;
typedef __attribute__((ext_vector_type(4)))  unsigned int uint4v;

__device__ __forceinline__ ushort_t f2bf(float f) {
    union { float f; unsigned int u; } v; v.f = f;
    unsigned int r = v.u + 0x7FFFu + ((v.u >> 16) & 1u);   // RNE
    return (ushort_t)(r >> 16);
}

// ---------- pre-pass: x (NCHW f32) -> x_t (NHWC bf16) ----------
// x strides (f32): n 2560000, ic 160000, i 8000, j 400, (k,l)=p 1
// x_t strides (bf16): n 2560000, i 128000, j 6400, p*16 + ic
__global__ __launch_bounds__(256) void xpose_x(const float* __restrict__ x,
                                               ushort_t* __restrict__ xt) {
    __shared__ ushort_t lt[6400];
    const int j = blockIdx.x, i = blockIdx.y, n = blockIdx.z;
    const int t = threadIdx.x;
    const float* xb = x + (size_t)n * 2560000 + (size_t)i * 8000 + (size_t)j * 400;
    #pragma unroll
    for (int ic = 0; ic < 16; ++ic) {
        const float* xr = xb + (size_t)ic * 160000;
        for (int s = t; s < 400; s += 256)
            lt[s * 16 + ic] = f2bf(xr[s]);
    }
    __syncthreads();
    uint4v* dst = (uint4v*)(xt + (size_t)n * 2560000 + (size_t)i * 128000 + (size_t)j * 6400);
    const uint4v* srcl = (const uint4v*)lt;
    for (int s = t; s < 800; s += 256) dst[s] = srcl[s];
}

// ---------- pre-pass: w (ic,oc,tap f32) -> w_t (tap,oc,ic bf16) ----------
__global__ __launch_bounds__(256) void xpose_w(const float* __restrict__ w,
                                               ushort_t* __restrict__ wt) {
    int s = blockIdx.x * 256 + threadIdx.x;
    if (s < 41472) {
        int ic = s / 2592, rem = s % 2592;
        int oc = rem / 81, tap = rem % 81;
        wt[tap * 512 + oc * 16 + ic] = f2bf(w[s]);
    }
}

// ---------- main conv ----------
__global__ __launch_bounds__(256, 3) void conv4d_mfma(
    const ushort_t* __restrict__ xt, const ushort_t* __restrict__ wt,
    float* __restrict__ out)
{
    __shared__ ushort_t lx[2][6400];   // double-buffered (k',l',ic) slab, 12.8KB each

    const int i = blockIdx.x, j = blockIdx.y, n = blockIdx.z;
    const int t = threadIdx.x;
    const int lane = t & 63, wv = t >> 6;
    const int col = lane & 31, ic8 = lane >> 5;

    // per-tile precompute (pos -> slab offset / out offset), invariant over taps
    int soff[3]; int pcs[3]; bool val[3];
    const int tbase = wv * 3;
    #pragma unroll
    for (int m = 0; m < 3; ++m) {
        int pos = (tbase + m) * 32 + col;
        val[m] = (pos < 324);
        int pc = val[m] ? pos : 323;
        int k_ = pc / 18, l_ = pc % 18;
        soff[m] = (k_ * 20 + l_) * 32 + ic8 * 16;  // BYTES into slab
        pcs[m] = pc;
    }

    f32x16 acc0, acc1, acc2;
    #pragma unroll
    for (int r = 0; r < 16; ++r) { acc0[r] = 0.0f; acc1[r] = 0.0f; acc2[r] = 0.0f; }

    const ushort_t* xbase = xt + (size_t)n * 2560000;

    // reg-staged prefetch of the 12.8KB slab: 800 16B chunks / 256 threads
    uint4v stg[4];
    {
        const uint4v* s4 = (const uint4v*)(xbase + (size_t)i * 128000 + (size_t)j * 6400);
        stg[0] = s4[t]; stg[1] = s4[t + 256]; stg[2] = s4[t + 512];
        if (t < 32) stg[3] = s4[t + 768];
    }
    {
        uint4v* d4 = (uint4v*)lx[0];
        d4[t] = stg[0]; d4[t + 256] = stg[1]; d4[t + 512] = stg[2];
        if (t < 32) d4[t + 768] = stg[3];
    }

    int cur = 0;
    for (int ab = 0; ab < 9; ++ab) {
        __syncthreads();   // slab[cur] visible; everyone done with slab[cur^1]

        // issue next slab's global loads early (hide HBM under compute)
        if (ab < 8) {
            int a = (ab + 1) / 3, b = (ab + 1) % 3;
            const uint4v* s4 = (const uint4v*)(xbase + (size_t)(i + a) * 128000 + (size_t)(j + b) * 6400);
            stg[0] = s4[t]; stg[1] = s4[t + 256]; stg[2] = s4[t + 512];
            if (t < 32) stg[3] = s4[t + 768];
        }

        // A fragments for this (a,b): 9 taps, straight from global (L2-resident)
        bf16x8 af[9];
        const ushort_t* wtb = wt + (ab * 9) * 512 + col * 16 + ic8 * 8;
        #pragma unroll
        for (int cd = 0; cd < 9; ++cd)
            af[cd] = *(const bf16x8*)(wtb + cd * 512);

        const char* lbase = (const char*)lx[cur];
        #pragma unroll
        for (int cd = 0; cd < 9; ++cd) {
            const int toff = ((cd / 3) * 20 + (cd % 3)) * 32;   // tap (c,d) byte shift
            bf16x8 bv0 = *(const bf16x8*)(lbase + soff[0] + toff);
            bf16x8 bv1 = *(const bf16x8*)(lbase + soff[1] + toff);
            bf16x8 bv2 = *(const bf16x8*)(lbase + soff[2] + toff);
            acc0 = __builtin_amdgcn_mfma_f32_32x32x16_bf16(af[cd], bv0, acc0, 0, 0, 0);
            acc1 = __builtin_amdgcn_mfma_f32_32x32x16_bf16(af[cd], bv1, acc1, 0, 0, 0);
            acc2 = __builtin_amdgcn_mfma_f32_32x32x16_bf16(af[cd], bv2, acc2, 0, 0, 0);
        }

        if (ab < 8) {
            uint4v* d4 = (uint4v*)lx[cur ^ 1];
            d4[t] = stg[0]; d4[t + 256] = stg[1]; d4[t + 512] = stg[2];
            if (t < 32) d4[t + 768] = stg[3];
            cur ^= 1;
        }
    }

    // epilogue: D layout col=lane&31, row=(r&3)+8*(r>>2)+4*(lane>>5)
    float* outn = out + (size_t)n * 32 * 104976 + (size_t)i * 5832 + (size_t)j * 324;
    #pragma unroll
    for (int m = 0; m < 3; ++m) {
        if (!val[m]) continue;
        const f32x16& am = (m == 0) ? acc0 : (m == 1) ? acc1 : acc2;
        float* ob = outn + pcs[m];
        #pragma unroll
        for (int r = 0; r < 16; ++r) {
            int oc = (r & 3) + 8 * (r >> 2) + 4 * ic8;
            ob[(size_t)oc * 104976] = am[r];
        }
    }
}

extern "C" void kernel_launch(void* const* d_in, const int* in_sizes, int n_in,
                              void* d_out, int out_size, void* d_ws, size_t ws_size,
                              hipStream_t stream) {
    const float* x = (const float*)d_in[0];
    const float* w = (const float*)d_in[1];
    float* out = (float*)d_out;

    ushort_t* xt = (ushort_t*)d_ws;
    ushort_t* wt = (ushort_t*)((char*)d_ws + (size_t)10240000);

    xpose_w<<<dim3(162), 256, 0, stream>>>(w, wt);
    xpose_x<<<dim3(20, 20, 2), 256, 0, stream>>>(x, xt);
    conv4d_mfma<<<dim3(18, 18, 2), 256, 0, stream>>>(xt, wt, out);
}

// Round 4
// 50.506 us; speedup vs baseline: 12.6138x; 1.1689x over previous
//
#include <hip/hip_runtime.h>

// Conv4d via implicit GEMM on MFMA (bf16 in, fp32 accum), shift-structured.
// x (2,16,20^4) f32, w (16,32,3^4) f32 -> out (2,32,18^4) f32
//
// R4 vs R3: the 3 d-taps (l-shifts) shared 97% of their B-fragments but each
// re-read LDS. Now: tiles live in SLAB space (32 contiguous slab positions ->
// contiguous 1KB ds_read spans, conflict-free), ONE B-frag feeds 3 MFMAs
// (d=0,1,2) into 3 accumulators; epilogue realigns with lane-shifts:
//   out(k,l) = sum_d acc_d[s = k*20 + l + d]
// LDS reads/block: 972KB -> 324KB. Wave-boundary edge values via LDS buffer.

typedef unsigned short ushort_t;
typedef __attribute__((ext_vector_type(8)))  __bf16 bf16x8;
typedef __attribute__((ext_vector_type(16))) float  f32x16;
typedef __attribute__((ext_vector_type(4)))  unsigned int uint4v;

__device__ __forceinline__ ushort_t f2bf(float f) {
    union { float f; unsigned int u; } v; v.f = f;
    unsigned int r = v.u + 0x7FFFu + ((v.u >> 16) & 1u);   // RNE
    return (ushort_t)(r >> 16);
}

// ---------- fused prepass ----------
// blocks 0..1249: x (NCHW f32) -> xt (N,spatial,ic bf16), LDS-free gather.
//   xt elem = (n*160000 + spatial)*16 + ic, spatial = i*8000+j*400+k*20+l
// blocks 1250..1411: w (ic,oc,tap f32) -> wt (tap,oc,ic bf16)
__global__ __launch_bounds__(256) void prepass(const float* __restrict__ x,
                                               const float* __restrict__ w,
                                               ushort_t* __restrict__ xt,
                                               ushort_t* __restrict__ wt) {
    const int blk = blockIdx.x;
    if (blk < 1250) {
        const int g = blk * 256 + threadIdx.x;          // 0..319999
        const int n = g / 160000, rem = g % 160000;
        const float* xs = x + (size_t)n * 2560000 + rem;
        unsigned int pk[8];
        #pragma unroll
        for (int e = 0; e < 8; ++e) {
            unsigned int lo = f2bf(xs[(size_t)(2 * e) * 160000]);
            unsigned int hi = f2bf(xs[(size_t)(2 * e + 1) * 160000]);
            pk[e] = lo | (hi << 16);
        }
        uint4v* q = (uint4v*)xt + (size_t)g * 2;
        uint4v q0; q0[0] = pk[0]; q0[1] = pk[1]; q0[2] = pk[2]; q0[3] = pk[3];
        uint4v q1; q1[0] = pk[4]; q1[1] = pk[5]; q1[2] = pk[6]; q1[3] = pk[7];
        q[0] = q0; q[1] = q1;
    } else {
        const int s = (blk - 1250) * 256 + threadIdx.x;
        if (s < 41472) {
            const int ic = s / 2592, rem = s % 2592;
            const int oc = rem / 81, tap = rem % 81;
            wt[tap * 512 + oc * 16 + ic] = f2bf(w[s]);
        }
    }
}

// ---------- main conv ----------
__global__ __launch_bounds__(256, 2) void conv4d_mfma(
    const ushort_t* __restrict__ xt, const ushort_t* __restrict__ wt,
    float* __restrict__ out)
{
    __shared__ ushort_t lx[2][6400];            // double-buffered slab, 12.8KB each
    __shared__ float edgebuf[4][3][2][16];      // [wv][e1|e2a|e2b][ic8][r]

    const int i = blockIdx.x, j = blockIdx.y, n = blockIdx.z;
    const int t = threadIdx.x;
    const int lane = t & 63, wv = t >> 6;
    const int col = lane & 31, ic8 = lane >> 5;

    // slab-pos per tile m (tiles T=3wv+m cover s in [32T, 32T+32))
    int sp[3];
    #pragma unroll
    for (int m = 0; m < 3; ++m) sp[m] = (3 * wv + m) * 32 + col;

    f32x16 acc[3][3];   // [d][m]
    #pragma unroll
    for (int d = 0; d < 3; ++d)
        #pragma unroll
        for (int m = 0; m < 3; ++m)
            #pragma unroll
            for (int r = 0; r < 16; ++r) acc[d][m][r] = 0.0f;

    const ushort_t* xbase = xt + (size_t)n * 2560000;

    // prologue: stage slab (a=0,b=0)
    uint4v stg[4];
    {
        const uint4v* s4 = (const uint4v*)(xbase + (size_t)i * 128000 + (size_t)j * 6400);
        stg[0] = s4[t]; stg[1] = s4[t + 256]; stg[2] = s4[t + 512];
        if (t < 32) stg[3] = s4[t + 768];
        uint4v* d4 = (uint4v*)lx[0];
        d4[t] = stg[0]; d4[t + 256] = stg[1]; d4[t + 512] = stg[2];
        if (t < 32) d4[t + 768] = stg[3];
    }

    int cur = 0;
    for (int ab = 0; ab < 9; ++ab) {
        __syncthreads();

        if (ab < 8) {   // issue next slab's loads early
            const int a = (ab + 1) / 3, b = (ab + 1) % 3;
            const uint4v* s4 = (const uint4v*)(xbase + (size_t)(i + a) * 128000 + (size_t)(j + b) * 6400);
            stg[0] = s4[t]; stg[1] = s4[t + 256]; stg[2] = s4[t + 512];
            if (t < 32) stg[3] = s4[t + 768];
        }

        // A frags: 9 taps (c,d) for this (a,b), from L2-resident wt
        bf16x8 af[9];
        const ushort_t* wtb = wt + (ab * 9) * 512 + col * 16 + ic8 * 8;
        #pragma unroll
        for (int cd = 0; cd < 9; ++cd)
            af[cd] = *(const bf16x8*)(wtb + cd * 512);

        const char* lbase = (const char*)lx[cur];
        #pragma unroll
        for (int c = 0; c < 3; ++c) {
            #pragma unroll
            for (int m = 0; m < 3; ++m) {
                int spos = sp[m] + c * 20;
                spos = spos > 399 ? 399 : spos;        // clamp; clamped vals never consumed
                bf16x8 bv = *(const bf16x8*)(lbase + spos * 32 + ic8 * 16);
                #pragma unroll
                for (int d = 0; d < 3; ++d)
                    acc[d][m] = __builtin_amdgcn_mfma_f32_32x32x16_bf16(af[c * 3 + d], bv, acc[d][m], 0, 0, 0);
            }
        }

        if (ab < 8) {
            uint4v* d4 = (uint4v*)lx[cur ^ 1];
            d4[t] = stg[0]; d4[t + 256] = stg[1]; d4[t + 512] = stg[2];
            if (t < 32) d4[t + 768] = stg[3];
            cur ^= 1;
        }
    }

    // ---- epilogue: out(k,l) = acc0[s] + acc1[s+1] + acc2[s+2], s=k*20+l ----
    // export first-tile edge cols for the previous wave
    if (col == 0) {
        #pragma unroll
        for (int r = 0; r < 16; ++r) {
            edgebuf[wv][0][ic8][r] = acc[1][0][r];
            edgebuf[wv][1][ic8][r] = acc[2][0][r];
        }
    } else if (col == 1) {
        #pragma unroll
        for (int r = 0; r < 16; ++r)
            edgebuf[wv][2][ic8][r] = acc[2][0][r];
    }
    __syncthreads();
    const int nw = wv < 3 ? wv + 1 : 3;   // wave3's import is never consumed

    bool valm[3]; float* po[3];
    float* outn = out + (size_t)n * 3359232 + (size_t)i * 5832 + (size_t)j * 324
                      + (size_t)ic8 * 419904;
    #pragma unroll
    for (int m = 0; m < 3; ++m) {
        const int s = sp[m];
        const int k = s / 20, ls = s % 20;
        valm[m] = (ls <= 17) && (s <= 359);
        po[m] = outn + k * 18 + ls;
    }
    const int src1 = (lane & 32) | ((col + 1) & 31);
    const int src2 = (lane & 32) | ((col + 2) & 31);

    #pragma unroll
    for (int r = 0; r < 16; ++r) {
        const float e1  = edgebuf[nw][0][ic8][r];
        const float e2a = edgebuf[nw][1][ic8][r];
        const float e2b = edgebuf[nw][2][ic8][r];
        float t1[4], t2[4];
        #pragma unroll
        for (int m = 0; m < 3; ++m) {
            t1[m] = __shfl(acc[1][m][r], src1, 64);
            t2[m] = __shfl(acc[2][m][r], src2, 64);
        }
        t1[3] = e1;
        t2[3] = (col == 30) ? e2a : e2b;
        const int offr = ((r & 3) + 8 * (r >> 2)) * 104976;
        #pragma unroll
        for (int m = 0; m < 3; ++m) {
            const float v1 = (col == 31) ? t1[m + 1] : t1[m];
            const float v2 = (col >= 30) ? t2[m + 1] : t2[m];
            const float res = acc[0][m][r] + v1 + v2;
            if (valm[m]) po[m][offr] = res;
        }
    }
}

extern "C" void kernel_launch(void* const* d_in, const int* in_sizes, int n_in,
                              void* d_out, int out_size, void* d_ws, size_t ws_size,
                              hipStream_t stream) {
    const float* x = (const float*)d_in[0];
    const float* w = (const float*)d_in[1];
    float* out = (float*)d_out;

    ushort_t* xt = (ushort_t*)d_ws;
    ushort_t* wt = (ushort_t*)((char*)d_ws + (size_t)10240000);

    prepass<<<dim3(1412), 256, 0, stream>>>(x, w, xt, wt);
    conv4d_mfma<<<dim3(18, 18, 2), 256, 0, stream>>>(xt, wt, out);
}

// Round 5
// 47.674 us; speedup vs baseline: 13.3631x; 1.0594x over previous
//
#include <hip/hip_runtime.h>

// Conv4d via implicit GEMM on MFMA (bf16 in, fp32 accum).
// x (2,16,20^4) f32, w (16,32,3^4) f32 -> out (2,32,18^4) f32
//
// out[oc][pos] = sum over 81 taps of W_tap[32 oc][16 ic] * X_tap[16 ic][32 pos]
//
// R5 vs R4: back to ONE accumulator set per tile (48 VGPR, not 144).
// d-shifts handled at ds_read time: slab-space tiles make the shifted read
// (spos + c*20 + d) a contiguous 1KB wave-span -> conflict-free (R3's
// conflicts were from out-space tiling, not the shifts). Epilogue needs no
// shfl/edgebuf. VGPR ~140 -> launch_bounds(256,3) -> 12 waves/CU.
// Plus bijective XCD swizzle (648 = 8*81): i-adjacent blocks share 2/3 of
// their slabs -> L2-local re-fetch.

typedef unsigned short ushort_t;
typedef __attribute__((ext_vector_type(8)))  __bf16 bf16x8;
typedef __attribute__((ext_vector_type(16))) float  f32x16;
typedef __attribute__((ext_vector_type(4)))  unsigned int uint4v;

__device__ __forceinline__ ushort_t f2bf(float f) {
    union { float f; unsigned int u; } v; v.f = f;
    unsigned int r = v.u + 0x7FFFu + ((v.u >> 16) & 1u);   // RNE
    return (ushort_t)(r >> 16);
}

// ---------- fused prepass ----------
// blocks 0..1249: x (NCHW f32) -> xt (N,spatial,ic bf16), LDS-free gather.
// blocks 1250..1411: w (ic,oc,tap f32) -> wt (tap,oc,ic bf16)
__global__ __launch_bounds__(256) void prepass(const float* __restrict__ x,
                                               const float* __restrict__ w,
                                               ushort_t* __restrict__ xt,
                                               ushort_t* __restrict__ wt) {
    const int blk = blockIdx.x;
    if (blk < 1250) {
        const int g = blk * 256 + threadIdx.x;          // 0..319999
        const int n = g / 160000, rem = g % 160000;
        const float* xs = x + (size_t)n * 2560000 + rem;
        unsigned int pk[8];
        #pragma unroll
        for (int e = 0; e < 8; ++e) {
            unsigned int lo = f2bf(xs[(size_t)(2 * e) * 160000]);
            unsigned int hi = f2bf(xs[(size_t)(2 * e + 1) * 160000]);
            pk[e] = lo | (hi << 16);
        }
        uint4v* q = (uint4v*)xt + (size_t)g * 2;
        uint4v q0; q0[0] = pk[0]; q0[1] = pk[1]; q0[2] = pk[2]; q0[3] = pk[3];
        uint4v q1; q1[0] = pk[4]; q1[1] = pk[5]; q1[2] = pk[6]; q1[3] = pk[7];
        q[0] = q0; q[1] = q1;
    } else {
        const int s = (blk - 1250) * 256 + threadIdx.x;
        if (s < 41472) {
            const int ic = s / 2592, rem = s % 2592;
            const int oc = rem / 81, tap = rem % 81;
            wt[tap * 512 + oc * 16 + ic] = f2bf(w[s]);
        }
    }
}

// ---------- main conv ----------
__global__ __launch_bounds__(256, 3) void conv4d_mfma(
    const ushort_t* __restrict__ xt, const ushort_t* __restrict__ wt,
    float* __restrict__ out)
{
    __shared__ ushort_t lx[2][6400];   // double-buffered slab, 12.8KB each

    // bijective XCD swizzle: 648 blocks = 8 XCDs x 81 contiguous tiles
    const int wgid = blockIdx.x;
    const int tile_ = (wgid & 7) * 81 + (wgid >> 3);
    const int n = tile_ / 324;
    const int rem_ = tile_ - n * 324;
    const int j = rem_ / 18, i = rem_ % 18;

    const int t = threadIdx.x;
    const int lane = t & 63, wv = t >> 6;
    const int col = lane & 31, ic8 = lane >> 5;

    // slab-pos per tile m (tiles T=3wv+m cover s in [32T, 32T+32))
    int sp0 = (3 * wv + 0) * 32 + col;
    int sp1 = (3 * wv + 1) * 32 + col;
    int sp2 = (3 * wv + 2) * 32 + col;
    // clamp so shifted reads (<= +42 pos) stay in slab; clamped lanes only
    // feed out-columns that are never stored (s>357 is invalid).
    const int cb0 = (sp0 > 357 ? 357 : sp0) * 32 + ic8 * 16;
    const int cb1 = (sp1 > 357 ? 357 : sp1) * 32 + ic8 * 16;
    const int cb2 = (sp2 > 357 ? 357 : sp2) * 32 + ic8 * 16;

    f32x16 acc0, acc1, acc2;
    #pragma unroll
    for (int r = 0; r < 16; ++r) { acc0[r] = 0.0f; acc1[r] = 0.0f; acc2[r] = 0.0f; }

    const ushort_t* xbase = xt + (size_t)n * 2560000;

    // prologue: stage slab (a=0,b=0)
    uint4v stg[4];
    {
        const uint4v* s4 = (const uint4v*)(xbase + (size_t)i * 128000 + (size_t)j * 6400);
        stg[0] = s4[t]; stg[1] = s4[t + 256]; stg[2] = s4[t + 512];
        if (t < 32) stg[3] = s4[t + 768];
        uint4v* d4 = (uint4v*)lx[0];
        d4[t] = stg[0]; d4[t + 256] = stg[1]; d4[t + 512] = stg[2];
        if (t < 32) d4[t + 768] = stg[3];
    }

    int cur = 0;
    for (int ab = 0; ab < 9; ++ab) {
        __syncthreads();

        if (ab < 8) {   // issue next slab's loads early (hide latency under MFMA)
            const int a = (ab + 1) / 3, b = (ab + 1) % 3;
            const uint4v* s4 = (const uint4v*)(xbase + (size_t)(i + a) * 128000 + (size_t)(j + b) * 6400);
            stg[0] = s4[t]; stg[1] = s4[t + 256]; stg[2] = s4[t + 512];
            if (t < 32) stg[3] = s4[t + 768];
        }

        // A frags: 9 taps (c,d) for this (a,b), from L2-resident wt
        bf16x8 af[9];
        const ushort_t* wtb = wt + (ab * 9) * 512 + col * 16 + ic8 * 8;
        #pragma unroll
        for (int cd = 0; cd < 9; ++cd)
            af[cd] = *(const bf16x8*)(wtb + cd * 512);

        const char* p0 = (const char*)lx[cur] + cb0;
        const char* p1 = (const char*)lx[cur] + cb1;
        const char* p2 = (const char*)lx[cur] + cb2;
        #pragma unroll
        for (int c = 0; c < 3; ++c) {
            #pragma unroll
            for (int d = 0; d < 3; ++d) {
                const int off = (c * 20 + d) * 32;     // static ds_read offset
                bf16x8 b0 = *(const bf16x8*)(p0 + off);
                bf16x8 b1 = *(const bf16x8*)(p1 + off);
                bf16x8 b2 = *(const bf16x8*)(p2 + off);
                acc0 = __builtin_amdgcn_mfma_f32_32x32x16_bf16(af[c * 3 + d], b0, acc0, 0, 0, 0);
                acc1 = __builtin_amdgcn_mfma_f32_32x32x16_bf16(af[c * 3 + d], b1, acc1, 0, 0, 0);
                acc2 = __builtin_amdgcn_mfma_f32_32x32x16_bf16(af[c * 3 + d], b2, acc2, 0, 0, 0);
            }
        }

        if (ab < 8) {
            uint4v* d4 = (uint4v*)lx[cur ^ 1];
            d4[t] = stg[0]; d4[t + 256] = stg[1]; d4[t + 512] = stg[2];
            if (t < 32) d4[t + 768] = stg[3];
            cur ^= 1;
        }
    }

    // ---- epilogue: direct store, D layout col=lane&31, row=(r&3)+8*(r>>2)+4*ic8
    float* outn = out + (size_t)n * 3359232 + (size_t)i * 5832 + (size_t)j * 324
                      + (size_t)ic8 * 419904;
    #pragma unroll
    for (int m = 0; m < 3; ++m) {
        const int s = (m == 0) ? sp0 : (m == 1) ? sp1 : sp2;
        const f32x16& am = (m == 0) ? acc0 : (m == 1) ? acc1 : acc2;
        const int k = s / 20, ls = s % 20;
        if (ls <= 17 && s <= 357) {
            float* po = outn + k * 18 + ls;
            #pragma unroll
            for (int r = 0; r < 16; ++r)
                po[(size_t)(((r & 3) + 8 * (r >> 2)) * 104976)] = am[r];
        }
    }
}

extern "C" void kernel_launch(void* const* d_in, const int* in_sizes, int n_in,
                              void* d_out, int out_size, void* d_ws, size_t ws_size,
                              hipStream_t stream) {
    const float* x = (const float*)d_in[0];
    const float* w = (const float*)d_in[1];
    float* out = (float*)d_out;

    ushort_t* xt = (ushort_t*)d_ws;
    ushort_t* wt = (ushort_t*)((char*)d_ws + (size_t)10240000);

    prepass<<<dim3(1412), 256, 0, stream>>>(x, w, xt, wt);
    conv4d_mfma<<<dim3(648), 256, 0, stream>>>(xt, wt, out);
}